// Round 4
// baseline (173.918 us; speedup 1.0000x reference)
//
#include <hip/hip_runtime.h>
#include <math.h>

#define NTOK 16384
#define DDIM 4096
#define NEXP 64
#define TAU  2e-4f
#define WS_LO 262144   // short-offset of the lo-plane inside d_ws
#define NCW  32        // chunks per wave (K/4 = 1024 k, 32-k chunks)

typedef short bf16x8 __attribute__((ext_vector_type(8)));
typedef float f32x4  __attribute__((ext_vector_type(4)));

__device__ __forceinline__ unsigned short bf16_rne(float f) {
  unsigned u = __float_as_uint(f);
  u += 0x7fffu + ((u >> 16) & 1u);
  return (unsigned short)(u >> 16);
}

__device__ __forceinline__ void split4(float4 v, uint2& hi, uint2& lo) {
  unsigned h0 = bf16_rne(v.x), h1 = bf16_rne(v.y), h2 = bf16_rne(v.z), h3 = bf16_rne(v.w);
  float r0 = v.x - __uint_as_float(h0 << 16);
  float r1 = v.y - __uint_as_float(h1 << 16);
  float r2 = v.z - __uint_as_float(h2 << 16);
  float r3 = v.w - __uint_as_float(h3 << 16);
  unsigned l0 = bf16_rne(r0), l1 = bf16_rne(r1), l2 = bf16_rne(r2), l3 = bf16_rne(r3);
  hi = make_uint2(h0 | (h1 << 16), h2 | (h3 << 16));
  lo = make_uint2(l0 | (l1 << 16), l2 | (l3 << 16));
}

__device__ __forceinline__ bf16x8 mk8(uint2 a, uint2 b) {
  union { uint4 u; bf16x8 v; } t;
  t.u = make_uint4(a.x, a.y, b.x, b.y);
  return t.v;
}

__device__ __forceinline__ bool better(float va, int ia, float vb, int ib) {
  return (va > vb) || (va == vb && ia < ib);
}
__device__ __forceinline__ bool betterd(double va, int ia, double vb, int ib) {
  return (va > vb) || (va == vb && ia < ib);
}
#define CE(va, ia, vb, ib) { if (better(vb, ib, va, ia)) { float _tv = va; va = vb; vb = _tv; int _ti = ia; ia = ib; ib = _ti; } }

// ---- kernel 1: split W (fp32) into bf16 hi/lo, MFMA-fragment-linear, once ----
// reader (chunk cc, group g, lane l) wants W[g*16+(l&15)][cc*32+(l>>4)*8+j], j=0..7
// hi short-offset: cc*2048 + g*512 + l*8 ; lo at +WS_LO
__global__ __launch_bounds__(256)
void presplit_w(const float* __restrict__ w, short* __restrict__ ws) {
  const int tid = blockIdx.x * 256 + threadIdx.x;  // 32768 threads
  const int e = tid >> 9;          // expert 0..63
  const int o = tid & 511;         // k-octet 0..511
  const int c = o >> 2, q = o & 3;
  const int l = (e & 15) + 16 * q;
  const int g = e >> 4;
  const float* src = w + (size_t)e * DDIM + o * 8;
  float4 v0 = *(const float4*)src;
  float4 v1 = *(const float4*)(src + 4);
  uint2 h0, s0, h1, s1;
  split4(v0, h0, s0);
  split4(v1, h1, s1);
  const int off = c * 2048 + g * 512 + l * 8;
  *(uint4*)(ws + off)         = make_uint4(h0.x, h0.y, h1.x, h1.y);
  *(uint4*)(ws + WS_LO + off) = make_uint4(s0.x, s0.y, s1.x, s1.y);
}

// ---- fp64 recompute for near-tie tokens (rare); executed by one full wave ----
__device__ __noinline__ void fixup_token(const float* __restrict__ x,
                                         const float* __restrict__ wgt,
                                         float* __restrict__ out_idx,
                                         float* __restrict__ out_wt,
                                         int tok, unsigned pk, int l) {
  const int e0 = pk & 255, e1 = (pk >> 8) & 255, e2 = (pk >> 16) & 255, e3 = (pk >> 24) & 255;
  const float* xr = x   + (size_t)tok * DDIM + l * 64;
  const float* w0 = wgt + (size_t)e0 * DDIM + l * 64;
  const float* w1 = wgt + (size_t)e1 * DDIM + l * 64;
  const float* w2 = wgt + (size_t)e2 * DDIM + l * 64;
  const float* w3 = wgt + (size_t)e3 * DDIM + l * 64;
  double s0 = 0.0, s1 = 0.0, s2 = 0.0, s3 = 0.0;
#pragma unroll 4
  for (int j = 0; j < 64; j += 4) {
    float4 xv = *(const float4*)(xr + j);
    float4 av = *(const float4*)(w0 + j);
    s0 = fma((double)xv.x, (double)av.x, s0); s0 = fma((double)xv.y, (double)av.y, s0);
    s0 = fma((double)xv.z, (double)av.z, s0); s0 = fma((double)xv.w, (double)av.w, s0);
    av = *(const float4*)(w1 + j);
    s1 = fma((double)xv.x, (double)av.x, s1); s1 = fma((double)xv.y, (double)av.y, s1);
    s1 = fma((double)xv.z, (double)av.z, s1); s1 = fma((double)xv.w, (double)av.w, s1);
    av = *(const float4*)(w2 + j);
    s2 = fma((double)xv.x, (double)av.x, s2); s2 = fma((double)xv.y, (double)av.y, s2);
    s2 = fma((double)xv.z, (double)av.z, s2); s2 = fma((double)xv.w, (double)av.w, s2);
    av = *(const float4*)(w3 + j);
    s3 = fma((double)xv.x, (double)av.x, s3); s3 = fma((double)xv.y, (double)av.y, s3);
    s3 = fma((double)xv.z, (double)av.z, s3); s3 = fma((double)xv.w, (double)av.w, s3);
  }
#pragma unroll
  for (int m = 1; m < 64; m <<= 1) {
    s0 += __shfl_xor(s0, m);
    s1 += __shfl_xor(s1, m);
    s2 += __shfl_xor(s2, m);
    s3 += __shfl_xor(s3, m);
  }
  if (l == 0) {
    double v0 = s0, v1 = s1, v2 = s2, v3 = s3;
    int i0 = e0, i1 = e1, i2 = e2, i3 = e3;
    if (betterd(v1, i1, v0, i0)) { double tv = v0; v0 = v1; v1 = tv; int ti = i0; i0 = i1; i1 = ti; }
    if (betterd(v3, i3, v2, i2)) { double tv = v2; v2 = v3; v3 = tv; int ti = i2; i2 = i3; i3 = ti; }
    if (betterd(v2, i2, v0, i0)) { double tv = v0; v0 = v2; v2 = tv; int ti = i0; i0 = i2; i2 = ti; }
    if (betterd(v3, i3, v1, i1)) { double tv = v1; v1 = v3; v3 = tv; int ti = i1; i1 = i3; i3 = ti; }
    if (betterd(v2, i2, v1, i1)) { double tv = v1; v1 = v2; v2 = tv; int ti = i1; i1 = i2; i2 = ti; }
    double ex = exp(v1 - v0);
    double den = 1.0 + ex;
    out_idx[tok * 2 + 0] = (float)i0;
    out_idx[tok * 2 + 1] = (float)i1;
    out_wt[tok * 2 + 0]  = (float)(1.0 / den);
    out_wt[tok * 2 + 1]  = (float)(ex / den);
  }
}

// ---- kernel 2: barrier-light streaming router GEMM + top-2 ----
// 1024 blocks x 256 thr (4 waves). Each wave: 16 tokens x 64 experts over K/4.
__global__ __launch_bounds__(256, 4)
void router_main(const float* __restrict__ x, const float* __restrict__ wgt,
                 const short* __restrict__ ws, float* __restrict__ out) {
  __shared__ float part[4][4][4][64];   // [wave][g][r][lane] — conflict-free both ways

  const int u = threadIdx.x;
  const int l = u & 63;
  const int wid = u >> 6;                    // K-quarter 0..3
  const int tokBase = blockIdx.x * 16;

  // A-fragment source: lane l reads X[tokBase+(l&15)][wid*1024 + cc*32 + (l>>4)*8 .. +8]
  const float* xp = x + (size_t)(tokBase + (l & 15)) * DDIM + wid * 1024 + ((l >> 4) * 8);
  // B-fragment source (pre-split): K-quarter wid starts at chunk wid*32 -> short offset wid*65536
  const short* whp = ws + wid * 65536 + l * 8;

  f32x4 acc[4];
#pragma unroll
  for (int g = 0; g < 4; ++g) acc[g] = (f32x4){0.f, 0.f, 0.f, 0.f};

#define LDW(WH, WL, cc)                                                        \
  { _Pragma("unroll")                                                          \
    for (int g = 0; g < 4; ++g) {                                              \
      WH[g] = *(const bf16x8*)(whp + (cc) * 2048 + g * 512);                   \
      WL[g] = *(const bf16x8*)(whp + WS_LO + (cc) * 2048 + g * 512);           \
    } }

// W loads issued BEFORE X loads within each step: vmcnt is FIFO, so waiting on
// W(c+2) must not force newer-needed X prefetches to drain.
#define STEP(X0, X1, WH, WL, cc)                                               \
  {                                                                            \
    uint2 h0, s0, h1, s1;                                                      \
    split4(X0, h0, s0);                                                        \
    split4(X1, h1, s1);                                                        \
    bf16x8 ahi = mk8(h0, h1);                                                  \
    bf16x8 alo = mk8(s0, s1);                                                  \
    _Pragma("unroll")                                                          \
    for (int g = 0; g < 4; ++g) {                                              \
      acc[g] = __builtin_amdgcn_mfma_f32_16x16x32_bf16(ahi, WH[g], acc[g], 0, 0, 0); \
      acc[g] = __builtin_amdgcn_mfma_f32_16x16x32_bf16(ahi, WL[g], acc[g], 0, 0, 0); \
      acc[g] = __builtin_amdgcn_mfma_f32_16x16x32_bf16(alo, WH[g], acc[g], 0, 0, 0); \
    }                                                                          \
    if ((cc) + 2 < NCW) { LDW(WH, WL, (cc) + 2) }                              \
    if ((cc) + 4 < NCW) {                                                      \
      X0 = *(const float4*)(xp + ((cc) + 4) * 32);                             \
      X1 = *(const float4*)(xp + ((cc) + 4) * 32 + 4);                         \
    }                                                                          \
  }

  // prologue: X 4 chunks deep, W 2 chunks deep
  float4 xA0 = *(const float4*)(xp + 0),  xA1 = *(const float4*)(xp + 4);
  float4 xB0 = *(const float4*)(xp + 32), xB1 = *(const float4*)(xp + 36);
  float4 xC0 = *(const float4*)(xp + 64), xC1 = *(const float4*)(xp + 68);
  float4 xD0 = *(const float4*)(xp + 96), xD1 = *(const float4*)(xp + 100);
  bf16x8 whA[4], wlA[4], whB[4], wlB[4];
  LDW(whA, wlA, 0)
  LDW(whB, wlB, 1)

  for (int c = 0; c < NCW; c += 4) {
    STEP(xA0, xA1, whA, wlA, c)
    STEP(xB0, xB1, whB, wlB, c + 1)
    STEP(xC0, xC1, whA, wlA, c + 2)
    STEP(xD0, xD1, whB, wlB, c + 3)
  }

  // ---- combine K-quarters through LDS; epilogue parallel across all 4 waves ----
#pragma unroll
  for (int g = 0; g < 4; ++g)
#pragma unroll
    for (int r = 0; r < 4; ++r)
      part[wid][g][r][l] = acc[g][r];
  __syncthreads();

  float* out_idx = out;
  float* out_wt  = out + NTOK * 2;
  float* out_lg  = out + NTOK * 4;

  // wave `wid` handles accumulator row r = wid -> tokens (l>>4)*4 + wid
  float v0, v1, v2, v3;
  {
    v0 = part[0][0][wid][l] + part[1][0][wid][l] + part[2][0][wid][l] + part[3][0][wid][l];
    v1 = part[0][1][wid][l] + part[1][1][wid][l] + part[2][1][wid][l] + part[3][1][wid][l];
    v2 = part[0][2][wid][l] + part[1][2][wid][l] + part[2][2][wid][l] + part[3][2][wid][l];
    v3 = part[0][3][wid][l] + part[1][3][wid][l] + part[2][3][wid][l] + part[3][3][wid][l];
  }
  const int tok = tokBase + (l >> 4) * 4 + wid;
  // logits (C layout: col = g*16 + (l&15), row = token)
  {
    float* dst = out_lg + (size_t)tok * NEXP + (l & 15);
    dst[0]  = v0;
    dst[16] = v1;
    dst[32] = v2;
    dst[48] = v3;
  }

  const int cbase = (l & 15);
  int i0 = cbase, i1 = cbase + 16, i2 = cbase + 32, i3 = cbase + 48;
  // in-lane sort-4 desc (indices ascending -> strict compare keeps low idx on tie)
  CE(v0, i0, v1, i1) CE(v2, i2, v3, i3) CE(v0, i0, v2, i2) CE(v1, i1, v3, i3) CE(v1, i1, v2, i2)
  // bitonic top-4 merge across the 16 lanes sharing this token
#pragma unroll
  for (int m = 1; m <= 8; m <<= 1) {
    float p0 = __shfl_xor(v0, m), p1 = __shfl_xor(v1, m);
    float p2 = __shfl_xor(v2, m), p3 = __shfl_xor(v3, m);
    int j0 = __shfl_xor(i0, m), j1 = __shfl_xor(i1, m);
    int j2 = __shfl_xor(i2, m), j3 = __shfl_xor(i3, m);
    CE(v0, i0, p3, j3) CE(v1, i1, p2, j2) CE(v2, i2, p1, j1) CE(v3, i3, p0, j0)
    CE(v0, i0, v2, i2) CE(v1, i1, v3, i3) CE(v0, i0, v1, i1) CE(v2, i2, v3, i3)
  }

  bool flag = false;
  unsigned pk = 0;
  if (cbase == 0) {
    flag = (v0 - v1 < TAU) || (v1 - v2 < TAU) || (v2 - v3 < TAU);
    pk = (unsigned)i0 | ((unsigned)i1 << 8) | ((unsigned)i2 << 16) | ((unsigned)i3 << 24);
    if (!flag) {
      float ex = expf(v1 - v0);
      float den = 1.0f + ex;
      out_idx[tok * 2 + 0] = (float)i0;
      out_idx[tok * 2 + 1] = (float)i1;
      out_wt[tok * 2 + 0]  = 1.0f / den;
      out_wt[tok * 2 + 1]  = ex / den;
    }
  }
  unsigned long long mk = __ballot(flag);
  while (mk) {
    const int src = __builtin_ctzll(mk);
    mk &= mk - 1;
    const unsigned p = (unsigned)__shfl((int)pk, src);
    fixup_token(x, wgt, out_idx, out_wt, tokBase + (src >> 4) * 4 + wid, p, l);
  }
}

extern "C" void kernel_launch(void* const* d_in, const int* in_sizes, int n_in,
                              void* d_out, int out_size, void* d_ws, size_t ws_size,
                              hipStream_t stream) {
  const float* x = (const float*)d_in[0];   // [4,4096,4096] f32
  const float* w = (const float*)d_in[1];   // [64,4096] f32
  float* out = (float*)d_out;               // 32768 idx + 32768 wt + 1048576 logits (all f32)
  short* ws = (short*)d_ws;                 // 1 MiB: bf16 hi/lo planes of W

  hipLaunchKernelGGL(presplit_w, dim3(128), dim3(256), 0, stream, w, ws);
  hipLaunchKernelGGL(router_main, dim3(NTOK / 16), dim3(256), 0, stream, x, w, ws, out);
}

// Round 5
// 88.039 us; speedup vs baseline: 1.9755x; 1.9755x over previous
//
#include <hip/hip_runtime.h>
#include <math.h>

#define NTOK 16384
#define DDIM 4096
#define NEXP 64
#define TAU  2e-4f
#define WS_LO 262144   // short-offset of the lo-plane inside d_ws
#define NCW  32        // chunks per K-quarter (1024 k / 32)

typedef short bf16x8 __attribute__((ext_vector_type(8)));
typedef float f32x4  __attribute__((ext_vector_type(4)));

__device__ __forceinline__ unsigned short bf16_rne(float f) {
  unsigned u = __float_as_uint(f);
  u += 0x7fffu + ((u >> 16) & 1u);
  return (unsigned short)(u >> 16);
}

__device__ __forceinline__ void split4(float4 v, uint2& hi, uint2& lo) {
  unsigned h0 = bf16_rne(v.x), h1 = bf16_rne(v.y), h2 = bf16_rne(v.z), h3 = bf16_rne(v.w);
  float r0 = v.x - __uint_as_float(h0 << 16);
  float r1 = v.y - __uint_as_float(h1 << 16);
  float r2 = v.z - __uint_as_float(h2 << 16);
  float r3 = v.w - __uint_as_float(h3 << 16);
  unsigned l0 = bf16_rne(r0), l1 = bf16_rne(r1), l2 = bf16_rne(r2), l3 = bf16_rne(r3);
  hi = make_uint2(h0 | (h1 << 16), h2 | (h3 << 16));
  lo = make_uint2(l0 | (l1 << 16), l2 | (l3 << 16));
}

__device__ __forceinline__ bf16x8 mk8(uint2 a, uint2 b) {
  union { uint4 u; bf16x8 v; } t;
  t.u = make_uint4(a.x, a.y, b.x, b.y);
  return t.v;
}

__device__ __forceinline__ void gld_lds16(const float* g, char* l) {
  __builtin_amdgcn_global_load_lds((const __attribute__((address_space(1))) void*)g,
                                   (__attribute__((address_space(3))) void*)l,
                                   16, 0, 0);
}

__device__ __forceinline__ bool better(float va, int ia, float vb, int ib) {
  return (va > vb) || (va == vb && ia < ib);
}
__device__ __forceinline__ bool betterd(double va, int ia, double vb, int ib) {
  return (va > vb) || (va == vb && ia < ib);
}
#define CE(va, ia, vb, ib) { if (better(vb, ib, va, ia)) { float _tv = va; va = vb; vb = _tv; int _ti = ia; ia = ib; ib = _ti; } }

// ---- kernel 1: split W (fp32) into bf16 hi/lo, MFMA-fragment-linear, once ----
__global__ __launch_bounds__(256)
void presplit_w(const float* __restrict__ w, short* __restrict__ ws) {
  const int tid = blockIdx.x * 256 + threadIdx.x;  // 32768 threads
  const int e = tid >> 9;          // expert 0..63
  const int o = tid & 511;         // k-octet 0..511
  const int c = o >> 2, q = o & 3;
  const int l = (e & 15) + 16 * q;
  const int g = e >> 4;
  const float* src = w + (size_t)e * DDIM + o * 8;
  float4 v0 = *(const float4*)src;
  float4 v1 = *(const float4*)(src + 4);
  uint2 h0, s0, h1, s1;
  split4(v0, h0, s0);
  split4(v1, h1, s1);
  const int off = c * 2048 + g * 512 + l * 8;
  *(uint4*)(ws + off)         = make_uint4(h0.x, h0.y, h1.x, h1.y);
  *(uint4*)(ws + WS_LO + off) = make_uint4(s0.x, s0.y, s1.x, s1.y);
}

// ---- fp64 recompute for near-tie tokens (rare); executed by one full wave ----
__device__ __noinline__ void fixup_token(const float* __restrict__ x,
                                         const float* __restrict__ wgt,
                                         float* __restrict__ out_idx,
                                         float* __restrict__ out_wt,
                                         int tok, unsigned pk, int l) {
  const int e0 = pk & 255, e1 = (pk >> 8) & 255, e2 = (pk >> 16) & 255, e3 = (pk >> 24) & 255;
  const float* xr = x   + (size_t)tok * DDIM + l * 64;
  const float* w0 = wgt + (size_t)e0 * DDIM + l * 64;
  const float* w1 = wgt + (size_t)e1 * DDIM + l * 64;
  const float* w2 = wgt + (size_t)e2 * DDIM + l * 64;
  const float* w3 = wgt + (size_t)e3 * DDIM + l * 64;
  double s0 = 0.0, s1 = 0.0, s2 = 0.0, s3 = 0.0;
#pragma unroll 4
  for (int j = 0; j < 64; j += 4) {
    float4 xv = *(const float4*)(xr + j);
    float4 av = *(const float4*)(w0 + j);
    s0 = fma((double)xv.x, (double)av.x, s0); s0 = fma((double)xv.y, (double)av.y, s0);
    s0 = fma((double)xv.z, (double)av.z, s0); s0 = fma((double)xv.w, (double)av.w, s0);
    av = *(const float4*)(w1 + j);
    s1 = fma((double)xv.x, (double)av.x, s1); s1 = fma((double)xv.y, (double)av.y, s1);
    s1 = fma((double)xv.z, (double)av.z, s1); s1 = fma((double)xv.w, (double)av.w, s1);
    av = *(const float4*)(w2 + j);
    s2 = fma((double)xv.x, (double)av.x, s2); s2 = fma((double)xv.y, (double)av.y, s2);
    s2 = fma((double)xv.z, (double)av.z, s2); s2 = fma((double)xv.w, (double)av.w, s2);
    av = *(const float4*)(w3 + j);
    s3 = fma((double)xv.x, (double)av.x, s3); s3 = fma((double)xv.y, (double)av.y, s3);
    s3 = fma((double)xv.z, (double)av.z, s3); s3 = fma((double)xv.w, (double)av.w, s3);
  }
#pragma unroll
  for (int m = 1; m < 64; m <<= 1) {
    s0 += __shfl_xor(s0, m);
    s1 += __shfl_xor(s1, m);
    s2 += __shfl_xor(s2, m);
    s3 += __shfl_xor(s3, m);
  }
  if (l == 0) {
    double v0 = s0, v1 = s1, v2 = s2, v3 = s3;
    int i0 = e0, i1 = e1, i2 = e2, i3 = e3;
    if (betterd(v1, i1, v0, i0)) { double tv = v0; v0 = v1; v1 = tv; int ti = i0; i0 = i1; i1 = ti; }
    if (betterd(v3, i3, v2, i2)) { double tv = v2; v2 = v3; v3 = tv; int ti = i2; i2 = i3; i3 = ti; }
    if (betterd(v2, i2, v0, i0)) { double tv = v0; v0 = v2; v2 = tv; int ti = i0; i0 = i2; i2 = ti; }
    if (betterd(v3, i3, v1, i1)) { double tv = v1; v1 = v3; v3 = tv; int ti = i1; i1 = i3; i3 = ti; }
    if (betterd(v2, i2, v1, i1)) { double tv = v1; v1 = v2; v2 = tv; int ti = i1; i1 = i2; i2 = ti; }
    double ex = exp(v1 - v0);
    double den = 1.0 + ex;
    out_idx[tok * 2 + 0] = (float)i0;
    out_idx[tok * 2 + 1] = (float)i1;
    out_wt[tok * 2 + 0]  = (float)(1.0 / den);
    out_wt[tok * 2 + 1]  = (float)(ex / den);
  }
}

// ---- kernel 2: barrier-free main loop; X staged via global_load_lds ring ----
// 512 blocks x 256 thr (4 waves = 4 K-quarters). Block = 32 tokens x 64 experts.
// Per wave LDS: 3 ring slots + 1 scratch slot, 4 KB each (chunk = 32 tok x 32 k fp32).
__global__ __launch_bounds__(256, 2)
void router_main(const float* __restrict__ x, const float* __restrict__ wgt,
                 const short* __restrict__ ws, float* __restrict__ out) {
  __shared__ __align__(16) char ldsbuf[65536];

  const int u = threadIdx.x;
  const int l = u & 63;
  const int wid = u >> 6;          // K-quarter 0..3
  const int tokBase = blockIdx.x * 32;
  const int row = l & 15;
  const int hq = l >> 4;

  char* ring = ldsbuf + wid * 16384;

  // per-lane global X sources for the 4 gld_lds issues (tile tt = j>>1, k-half = j&1)
  const float* xb0 = x + (size_t)(tokBase +  0 + row) * DDIM + wid * 1024 +  0 + hq * 4;
  const float* xb1 = x + (size_t)(tokBase +  0 + row) * DDIM + wid * 1024 + 16 + hq * 4;
  const float* xb2 = x + (size_t)(tokBase + 16 + row) * DDIM + wid * 1024 +  0 + hq * 4;
  const float* xb3 = x + (size_t)(tokBase + 16 + row) * DDIM + wid * 1024 + 16 + hq * 4;

  const short* whp = ws + wid * 65536 + l * 8;

  // A-fragment byte offset inside a (slot, tt) 2 KB block
  const int dsoff = (hq >> 1) * 1024 + ((hq & 1) * 32 + row) * 16;

  f32x4 acc[2][4];
#pragma unroll
  for (int tt = 0; tt < 2; ++tt)
#pragma unroll
    for (int g = 0; g < 4; ++g) acc[tt][g] = (f32x4){0.f, 0.f, 0.f, 0.f};

  bf16x8 whA[4], wlA[4], whB[4], wlB[4];

#define LDW(WH, WL, cc)                                                        \
  { _Pragma("unroll")                                                          \
    for (int g = 0; g < 4; ++g) {                                              \
      WH[g] = *(const bf16x8*)(whp + (cc) * 2048 + g * 512);                   \
      WL[g] = *(const bf16x8*)(whp + WS_LO + (cc) * 2048 + g * 512);           \
    } }

  // prologue, order-pinned: [X0 gld x4][W0 x8][X1 gld x4][W1 x8]
  gld_lds16(xb0, ring);
  gld_lds16(xb1, ring + 1024);
  gld_lds16(xb2, ring + 2048);
  gld_lds16(xb3, ring + 3072);
  asm volatile("" ::: "memory");
  LDW(whA, wlA, 0)
  asm volatile("" ::: "memory");
  gld_lds16(xb0 + 32, ring + 4096);
  gld_lds16(xb1 + 32, ring + 4096 + 1024);
  gld_lds16(xb2 + 32, ring + 4096 + 2048);
  gld_lds16(xb3 + 32, ring + 4096 + 3072);
  asm volatile("" ::: "memory");
  LDW(whB, wlB, 1)

  int slr = 0;  // read slot  = s % 3
  int slw = 2;  // write slot = (s+2) % 3

  // per step s: [4 gld X(s+2)] [vmcnt(16) => X(s),W(s) done] [compute] [8 ld W(s+2)]
  // exactly 16 vmem issues separate W(s) from its consuming wait => vmcnt(16) uniform.
#define STEP(S, WH, WL)                                                        \
  {                                                                            \
    asm volatile("" ::: "memory");                                             \
    const int chx = (S) + 2;                                                   \
    char* xdst = ring + ((chx < NCW) ? slw : 3) * 4096;                        \
    const int xofs = ((chx < NCW) ? chx : (NCW - 1)) * 32;                     \
    gld_lds16(xb0 + xofs, xdst);                                               \
    gld_lds16(xb1 + xofs, xdst + 1024);                                        \
    gld_lds16(xb2 + xofs, xdst + 2048);                                        \
    gld_lds16(xb3 + xofs, xdst + 3072);                                        \
    asm volatile("s_waitcnt vmcnt(16)" ::: "memory");                          \
    const char* rb = ring + slr * 4096;                                        \
    {                                                                          \
      float4 f0 = *(const float4*)(rb + dsoff);                                \
      float4 f1 = *(const float4*)(rb + dsoff + 256);                          \
      uint2 h0, s0, h1, s1;                                                    \
      split4(f0, h0, s0); split4(f1, h1, s1);                                  \
      bf16x8 ahi = mk8(h0, h1), alo = mk8(s0, s1);                             \
      _Pragma("unroll")                                                        \
      for (int g = 0; g < 4; ++g) {                                            \
        acc[0][g] = __builtin_amdgcn_mfma_f32_16x16x32_bf16(ahi, WH[g], acc[0][g], 0, 0, 0); \
        acc[0][g] = __builtin_amdgcn_mfma_f32_16x16x32_bf16(ahi, WL[g], acc[0][g], 0, 0, 0); \
        acc[0][g] = __builtin_amdgcn_mfma_f32_16x16x32_bf16(alo, WH[g], acc[0][g], 0, 0, 0); \
      }                                                                        \
    }                                                                          \
    {                                                                          \
      float4 f0 = *(const float4*)(rb + 2048 + dsoff);                         \
      float4 f1 = *(const float4*)(rb + 2048 + dsoff + 256);                   \
      uint2 h0, s0, h1, s1;                                                    \
      split4(f0, h0, s0); split4(f1, h1, s1);                                  \
      bf16x8 ahi = mk8(h0, h1), alo = mk8(s0, s1);                             \
      _Pragma("unroll")                                                        \
      for (int g = 0; g < 4; ++g) {                                            \
        acc[1][g] = __builtin_amdgcn_mfma_f32_16x16x32_bf16(ahi, WH[g], acc[1][g], 0, 0, 0); \
        acc[1][g] = __builtin_amdgcn_mfma_f32_16x16x32_bf16(ahi, WL[g], acc[1][g], 0, 0, 0); \
        acc[1][g] = __builtin_amdgcn_mfma_f32_16x16x32_bf16(alo, WH[g], acc[1][g], 0, 0, 0); \
      }                                                                        \
    }                                                                          \
    const int chw = ((S) + 2 < NCW) ? (S) + 2 : (NCW - 1);                     \
    asm volatile("" ::: "memory");                                             \
    LDW(WH, WL, chw)                                                           \
    slr = (slr == 2) ? 0 : slr + 1;                                            \
    slw = (slw == 2) ? 0 : slw + 1;                                            \
  }

  for (int s = 0; s < NCW; s += 2) {
    STEP(s, whA, wlA)
    STEP(s + 1, whB, wlB)
  }

  // ---- combine K-quarters through LDS (aliased over the ring) ----
  __syncthreads();   // all waves done with their rings
  float* p = (float*)ldsbuf;
#define PIDX(KQ, TT, G, R) ((((((KQ) * 2 + (TT)) * 4 + (G)) * 4 + (R)) << 6) + l)
#pragma unroll
  for (int tt = 0; tt < 2; ++tt)
#pragma unroll
    for (int g = 0; g < 4; ++g)
#pragma unroll
      for (int r = 0; r < 4; ++r)
        p[PIDX(wid, tt, g, r)] = acc[tt][g][r];
  __syncthreads();

  float* out_idx = out;
  float* out_wt  = out + NTOK * 2;
  float* out_lg  = out + NTOK * 4;

  // wave `wid` handles accumulator row r = wid, for both token tiles
#pragma unroll
  for (int tt = 0; tt < 2; ++tt) {
    float v0 = p[PIDX(0, tt, 0, wid)] + p[PIDX(1, tt, 0, wid)] + p[PIDX(2, tt, 0, wid)] + p[PIDX(3, tt, 0, wid)];
    float v1 = p[PIDX(0, tt, 1, wid)] + p[PIDX(1, tt, 1, wid)] + p[PIDX(2, tt, 1, wid)] + p[PIDX(3, tt, 1, wid)];
    float v2 = p[PIDX(0, tt, 2, wid)] + p[PIDX(1, tt, 2, wid)] + p[PIDX(2, tt, 2, wid)] + p[PIDX(3, tt, 2, wid)];
    float v3 = p[PIDX(0, tt, 3, wid)] + p[PIDX(1, tt, 3, wid)] + p[PIDX(2, tt, 3, wid)] + p[PIDX(3, tt, 3, wid)];

    const int tok = tokBase + tt * 16 + (l >> 4) * 4 + wid;
    {
      float* dst = out_lg + (size_t)tok * NEXP + (l & 15);
      dst[0]  = v0;
      dst[16] = v1;
      dst[32] = v2;
      dst[48] = v3;
    }

    const int cbase = (l & 15);
    int i0 = cbase, i1 = cbase + 16, i2 = cbase + 32, i3 = cbase + 48;
    CE(v0, i0, v1, i1) CE(v2, i2, v3, i3) CE(v0, i0, v2, i2) CE(v1, i1, v3, i3) CE(v1, i1, v2, i2)
#pragma unroll
    for (int m = 1; m <= 8; m <<= 1) {
      float p0 = __shfl_xor(v0, m), p1 = __shfl_xor(v1, m);
      float p2 = __shfl_xor(v2, m), p3 = __shfl_xor(v3, m);
      int j0 = __shfl_xor(i0, m), j1 = __shfl_xor(i1, m);
      int j2 = __shfl_xor(i2, m), j3 = __shfl_xor(i3, m);
      CE(v0, i0, p3, j3) CE(v1, i1, p2, j2) CE(v2, i2, p1, j1) CE(v3, i3, p0, j0)
      CE(v0, i0, v2, i2) CE(v1, i1, v3, i3) CE(v0, i0, v1, i1) CE(v2, i2, v3, i3)
    }

    bool flag = false;
    unsigned pk = 0;
    if (cbase == 0) {
      flag = (v0 - v1 < TAU) || (v1 - v2 < TAU) || (v2 - v3 < TAU);
      pk = (unsigned)i0 | ((unsigned)i1 << 8) | ((unsigned)i2 << 16) | ((unsigned)i3 << 24);
      if (!flag) {
        float ex = expf(v1 - v0);
        float den = 1.0f + ex;
        out_idx[tok * 2 + 0] = (float)i0;
        out_idx[tok * 2 + 1] = (float)i1;
        out_wt[tok * 2 + 0]  = 1.0f / den;
        out_wt[tok * 2 + 1]  = ex / den;
      }
    }
    unsigned long long mk = __ballot(flag);
    while (mk) {
      const int src = __builtin_ctzll(mk);
      mk &= mk - 1;
      const unsigned pks = (unsigned)__shfl((int)pk, src);
      fixup_token(x, wgt, out_idx, out_wt, tokBase + tt * 16 + (src >> 4) * 4 + wid, pks, l);
    }
  }
}

extern "C" void kernel_launch(void* const* d_in, const int* in_sizes, int n_in,
                              void* d_out, int out_size, void* d_ws, size_t ws_size,
                              hipStream_t stream) {
  const float* x = (const float*)d_in[0];   // [4,4096,4096] f32
  const float* w = (const float*)d_in[1];   // [64,4096] f32
  float* out = (float*)d_out;               // 32768 idx + 32768 wt + 1048576 logits (all f32)
  short* ws = (short*)d_ws;                 // 1 MiB: bf16 hi/lo planes of W

  hipLaunchKernelGGL(presplit_w, dim3(128), dim3(256), 0, stream, w, ws);
  hipLaunchKernelGGL(router_main, dim3(NTOK / 32), dim3(256), 0, stream, x, w, ws, out);
}